// Round 17
// baseline (202.552 us; speedup 1.0000x reference)
//
#include <hip/hip_runtime.h>
#include <math.h>

#define DD 128
#define CAP 10240
#define KVS 256  // KV row: 128 K-fp8 + 128 V-u8, 256B-aligned (exactly 4 lines)
typedef unsigned int u32;
typedef unsigned short u16;
typedef __attribute__((ext_vector_type(8))) short bf16x8;
typedef __attribute__((ext_vector_type(4))) float f32x4;
typedef __attribute__((ext_vector_type(2))) float f32x2;

__device__ __forceinline__ float4 f4zero() { return make_float4(0.f, 0.f, 0.f, 0.f); }
// round-to-nearest-even f32 -> bf16 (low 16 bits)
__device__ __forceinline__ u32 bf16rne(float f) {
    u32 u = __float_as_uint(f);
    u += 0x7FFFu + ((u >> 16) & 1u);
    return u >> 16;
}
__device__ __forceinline__ u32 pack2(float lo, float hi) {
    return bf16rne(lo) | (bf16rne(hi) << 16);
}
__device__ __forceinline__ float unlo(u32 u) { return __uint_as_float(u << 16); }
__device__ __forceinline__ float unhi(u32 u) { return __uint_as_float(u & 0xFFFF0000u); }
// byte -> float; LLVM pattern-matches to v_cvt_f32_ubyte0..3
__device__ __forceinline__ float ub0(u32 v) { return (float)(v & 0xFFu); }
__device__ __forceinline__ float ub1(u32 v) { return (float)((v >> 8) & 0xFFu); }
__device__ __forceinline__ float ub2(u32 v) { return (float)((v >> 16) & 0xFFu); }
__device__ __forceinline__ float ub3(u32 v) { return (float)(v >> 24); }

// ---------------------------------------------------------------------------
// Fused pre: compose_frags (blocks 0..29, 4 sub-bids each = 120) || p1_bucket.
// B' sections: Q = Wq@We1 ; K = Wk@We1 / Wp2@We1 / bp2@We1+be1 ;
//              V = Wv@Wo / Wp2@Wo / bp2@Wo   (VPo folding)
// ---------------------------------------------------------------------------
__global__ __launch_bounds__(256) void fused_pre(
    const float* __restrict__ Wq, const float* __restrict__ Wk,
    const float* __restrict__ Wv, const float* __restrict__ We1,
    const float* __restrict__ be1, const float* __restrict__ Wp2,
    const float* __restrict__ bp2, const float* __restrict__ Wo,
    u32* __restrict__ BF,
    const int* __restrict__ src, const int* __restrict__ dst,
    int* __restrict__ gcount, u32* __restrict__ ebuf, int E) {
    const int t = threadIdx.x;
    if (blockIdx.x < 30) {
        const int bid = blockIdx.x * 4 + (t >> 6);  // 0..119
        const int l = t & 63;
        const int c = l & 15;
        const int kg = l >> 4;
        float val[8];

        const int ct = bid / 5, ks = bid - ct * 5;
        const int u = ct / 6, r = ct - u * 6;
        const int n = 32 * u + 16 * (r < 2 ? r : (r & 1)) + c;
#pragma unroll
        for (int j = 0; j < 8; ++j) {
            const int k = ks * 32 + kg * 8 + j;
            float v = 0.f;
            if (r < 2) {  // Q section
                if (k < 128) {
                    float a = 0.f;
                    for (int q = 0; q < 128; ++q)
                        a = fmaf(Wq[k * 128 + q], We1[q * 128 + n], a);
                    v = a;
                }
            } else if (r < 4) {  // K section
                if (k < 128) {
                    float a = 0.f;
                    for (int q = 0; q < 128; ++q)
                        a = fmaf(Wk[k * 128 + q], We1[q * 128 + n], a);
                    v = a;
                } else if (k < 131) {
                    float a = 0.f;
                    for (int q = 0; q < 128; ++q)
                        a = fmaf(Wp2[(k - 128) * 128 + q], We1[q * 128 + n], a);
                    v = a;
                } else if (k == 131) {
                    float a = be1[n];
                    for (int q = 0; q < 128; ++q)
                        a = fmaf(bp2[q], We1[q * 128 + n], a);
                    v = a;
                }
            } else {  // V section -> VPo rows (folded with Wo)
                if (k < 128) {
                    float a = 0.f;
                    for (int q = 0; q < 128; ++q)
                        a = fmaf(Wv[k * 128 + q], Wo[q * 128 + n], a);
                    v = a;
                } else if (k < 131) {
                    float a = 0.f;
                    for (int q = 0; q < 128; ++q)
                        a = fmaf(Wp2[(k - 128) * 128 + q], Wo[q * 128 + n], a);
                    v = a;
                } else if (k == 131) {
                    float a = 0.f;
                    for (int q = 0; q < 128; ++q)
                        a = fmaf(bp2[q], Wo[q * 128 + n], a);
                    v = a;
                }
            }
            val[j] = v;
        }
        u32* dp = &BF[((size_t)bid * 64 + l) * 4];
        dp[0] = pack2(val[0], val[1]);
        dp[1] = pack2(val[2], val[3]);
        dp[2] = pack2(val[4], val[5]);
        dp[3] = pack2(val[6], val[7]);
    } else {
        // ---- p1_bucket: LDS-ranked coarse bucket (dst>>9) ----
        __shared__ int hist[256];
        __shared__ int base[256];
        hist[t] = 0;
        __syncthreads();
        const int chunk = (blockIdx.x - 30) * 4096;
        int bk[16], rk[16];
        u32 pv[16];
#pragma unroll
        for (int i = 0; i < 16; ++i) {
            int idx = chunk + i * 256 + t;
            bk[i] = -1;
            if (idx < E) {
                int dd = dst[idx];
                int ss = src[idx];
                bk[i] = dd >> 9;
                pv[i] = ((u32)ss << 9) | (u32)(dd & 511);
                rk[i] = atomicAdd(&hist[bk[i]], 1);
            }
        }
        __syncthreads();
        if (hist[t]) base[t] = t * CAP + atomicAdd(&gcount[t], hist[t]);
        __syncthreads();
#pragma unroll
        for (int i = 0; i < 16; ++i) {
            if (bk[i] >= 0) ebuf[base[bk[i]] + rk[i]] = pv[i];
        }
    }
}

// ---------------------------------------------------------------------------
// Fused mid: p2_local (blocks 0..NR-1) || node_mfma (rest).
// p2 computes its own 256-bucket exclusive scan from gcount (scanB removed).
// GEMM epilogue: QWb bf16-pair; KV row (256 B): [0,128) K fp8 slot-ordered,
// [128,256) VPo int8 (biased u8). PER-NODE scale -> Sb[N] (L2-resident).
// ---------------------------------------------------------------------------
__global__ __launch_bounds__(256) void fused_mid(
    const float* __restrict__ h, const float* __restrict__ c,
    const float* __restrict__ Wp1, const float* __restrict__ bp1,
    const u32* __restrict__ BF,
    u32* __restrict__ QWb, unsigned char* __restrict__ KV,
    float* __restrict__ Sb, int N,
    const int* __restrict__ gcount,
    const u32* __restrict__ ebuf, int* __restrict__ ssrc,
    int* __restrict__ offs, int E, int NR) {
    __shared__ u32 lds[64 * 96];  // 24 KB, aliased by both paths
    const int t = threadIdx.x;

    if ((int)blockIdx.x < NR) {
        // ---- p2_local: per-bucket CSR finalize ----
        int* cnt = (int*)lds;        // 512
        int* cur = cnt + 512;        // 512
        int* ts = cur + 512;         // 256
        const int r = blockIdx.x;

        // in-block exclusive scan of gcount -> base_r (replaces scanB kernel)
        ts[t] = gcount[t];
        __syncthreads();
        for (int off = 1; off < 256; off <<= 1) {
            int x = (t >= off) ? ts[t - off] : 0;
            __syncthreads();
            ts[t] += x;
            __syncthreads();
        }
        const int cnt_r = gcount[r];
        const int base_r = ts[r] - cnt_r;

        cnt[t] = 0;
        cnt[t + 256] = 0;
        __syncthreads();
        const u32* eb = &ebuf[(size_t)r * CAP];
        for (int i = t; i < cnt_r; i += 256) atomicAdd(&cnt[eb[i] & 511], 1);
        __syncthreads();
        int v0 = cnt[2 * t], v1 = cnt[2 * t + 1];
        int pair = v0 + v1;
        ts[t] = pair;
        __syncthreads();
        for (int off = 1; off < 256; off <<= 1) {
            int x = (t >= off) ? ts[t - off] : 0;
            __syncthreads();
            ts[t] += x;
            __syncthreads();
        }
        int ex = ts[t] - pair;
        cur[2 * t] = ex;
        cur[2 * t + 1] = ex + v0;
        offs[r * 512 + 2 * t] = base_r + ex;
        offs[r * 512 + 2 * t + 1] = base_r + ex + v0;
        if (r == NR - 1 && t == 255) offs[NR * 512] = E;
        __syncthreads();
        for (int i = t; i < cnt_r; i += 256) {
            u32 e = eb[i];
            int p = atomicAdd(&cur[e & 511], 1);
            ssrc[base_r + p] = (int)(e >> 9);
        }
        // zero the 8-entry pad (valid indices) so aggregate's prefetch is unguarded
        if (r == NR - 1 && t < 8) ssrc[E + t] = 0;
    } else {
        // ---- node_mfma: [N x 160] @ [160 x 384] bf16 MFMA GEMM ----
        u32* hs = lds;
        const int row0 = ((int)blockIdx.x - NR) * 64;

#pragma unroll
        for (int i = 0; i < 8; ++i) {
            int f = t + i * 256;
            int row = f >> 5;
            int cq = f & 31;
            float4 v = f4zero();
            if (row0 + row < N) v = *(const float4*)&h[(size_t)(row0 + row) * DD + cq * 4];
            int idx = row * 96 + ((cq * 2) ^ ((row & 7) << 2));
            uint2 p;
            p.x = pack2(v.x, v.y);
            p.y = pack2(v.z, v.w);
            *(uint2*)&hs[idx] = p;
        }
        if (t < 64) {
            int row = t;
            float u0 = 0.f, u1 = 0.f, u2 = 0.f;
            if (row0 + row < N) {
                const float* cr = &c[(size_t)(row0 + row) * 3];
                float c0 = cr[0], c1 = cr[1], c2 = cr[2];
                u0 = fmaxf(bp1[0] + c0 * Wp1[0] + c1 * Wp1[3] + c2 * Wp1[6], 0.f);
                u1 = fmaxf(bp1[1] + c0 * Wp1[1] + c1 * Wp1[4] + c2 * Wp1[7], 0.f);
                u2 = fmaxf(bp1[2] + c0 * Wp1[2] + c1 * Wp1[5] + c2 * Wp1[8], 0.f);
            }
            int swz = (row & 7) << 2;
            uint4 z0 = make_uint4(pack2(u0, u1), pack2(u2, 1.0f), 0u, 0u);
            uint4 zz = make_uint4(0u, 0u, 0u, 0u);
#pragma unroll
            for (int q = 0; q < 4; ++q) {
                int idx = row * 96 + 64 + ((q * 4) ^ swz);
                *(uint4*)&hs[idx] = (q == 0) ? z0 : zz;
            }
        }
        __syncthreads();

        const int w = t >> 6, l = t & 63;
        const int cc = l & 15, kg = l >> 4;

        f32x4 acc[4][6];
#pragma unroll
        for (int rt = 0; rt < 4; ++rt)
#pragma unroll
            for (int r = 0; r < 6; ++r) acc[rt][r] = (f32x4){0.f, 0.f, 0.f, 0.f};

#pragma unroll
        for (int ks = 0; ks < 5; ++ks) {
            bf16x8 a[4];
#pragma unroll
            for (int rt = 0; rt < 4; ++rt) {
                int row = rt * 16 + cc;
                int idx = row * 96 + ((ks * 16 + kg * 4) ^ ((row & 7) << 2));
                a[rt] = *(const bf16x8*)&hs[idx];
            }
#pragma unroll
            for (int r = 0; r < 6; ++r) {
                const bf16x8 b = *(const bf16x8*)&BF[(((size_t)(w * 6 + r) * 5 + ks) * 64 + l) * 4];
#pragma unroll
                for (int rt = 0; rt < 4; ++rt)
                    acc[rt][r] = __builtin_amdgcn_mfma_f32_16x16x32_bf16(a[rt], b, acc[rt][r], 0, 0, 0);
            }
        }

        // ---- per-row |V|max: shfl-reduce over 16 cc-lanes, then non-atomic
        //      cross-wave max via LDS (distinct slots, no contention) ----
        __syncthreads();  // all waves done reading hs
        float* ldsM = (float*)lds;  // [64 rows][4 waves]
#pragma unroll
        for (int rt = 0; rt < 4; ++rt) {
#pragma unroll
            for (int j = 0; j < 4; ++j) {
                float m = fmaxf(fabsf(acc[rt][4][j]), fabsf(acc[rt][5][j]));
                m = fmaxf(m, __shfl_xor(m, 1));
                m = fmaxf(m, __shfl_xor(m, 2));
                m = fmaxf(m, __shfl_xor(m, 4));
                m = fmaxf(m, __shfl_xor(m, 8));
                if (cc == 0) ldsM[(rt * 16 + kg * 4 + j) * 4 + w] = m;
            }
        }
        __syncthreads();

#pragma unroll
        for (int rt = 0; rt < 4; ++rt) {
#pragma unroll
            for (int j = 0; j < 4; ++j) {
                int rl = rt * 16 + kg * 4 + j;
                int row = row0 + rl;
                if (row >= N) continue;
                float smax = fmaxf(fmaxf(ldsM[rl * 4 + 0], ldsM[rl * 4 + 1]),
                                   fmaxf(ldsM[rl * 4 + 2], ldsM[rl * 4 + 3]));
                float scale = (smax > 0.f) ? smax * (1.0f / 127.0f) : 1.0f;
                float rsc = 1.0f / scale;
                QWb[(size_t)row * 64 + w * 16 + cc] = pack2(acc[rt][0][j], acc[rt][1][j]);
                unsigned char* kvrow = &KV[(size_t)row * KVS];
                u32 kp = __builtin_amdgcn_cvt_pk_fp8_f32(acc[rt][2][j], acc[rt][3][j], 0u, false);
                *(u16*)&kvrow[w * 32 + cc * 2] = (u16)kp;
                int q0 = (int)rintf(acc[rt][4][j] * rsc) + 128;
                int q1 = (int)rintf(acc[rt][5][j] * rsc) + 128;
                *(u16*)&kvrow[128 + 2 * (w * 16 + cc)] = (u16)((q0 & 0xFF) | ((q1 & 0xFF) << 8));
                if (w == 0 && cc == 0) Sb[row] = scale;
            }
        }
    }
}

// ---------------------------------------------------------------------------
// Aggregate: quarter-wave (16-lane) groups, 4 edges in flight/wave.
// Gathers 256B-aligned KV row (fp8 K 8B + u8 V 8B per lane) + per-NODE scale
// from Sb[N] (L2 hit). We2 indexed directly (lane i -> cols base / base+16).
// Unguarded index prefetch (ssrc padded with 8 valid entries). fp32 out.
// ---------------------------------------------------------------------------
__global__ __launch_bounds__(256) void aggregate(
    const int* __restrict__ offs, const int* __restrict__ ssrc,
    const unsigned char* __restrict__ KV, const float* __restrict__ Sb,
    const u32* __restrict__ QWb, const float* __restrict__ We2,
    const float* __restrict__ be2, const float* __restrict__ bo,
    float* __restrict__ out, int N) {
    const int node = (blockIdx.x * 256 + threadIdx.x) >> 6;
    const int lane = threadIdx.x & 63;
    if (node >= N) return;
    const int g = lane >> 4, i = lane & 15;

    const float SC = 0.08838834764831845f * 1.4426950408889634f;  // (1/sqrt128)*log2e
    const float CL = 5.0f * 1.4426950408889634f;

    uint4 Qu = *(const uint4*)&QWb[(size_t)node * 64 + 4 * i];
    f32x2 q01 = {unlo(Qu.x), unhi(Qu.x)};
    f32x2 q23 = {unlo(Qu.y), unhi(Qu.y)};
    f32x2 q45 = {unlo(Qu.z), unhi(Qu.z)};
    f32x2 q67 = {unlo(Qu.w), unhi(Qu.w)};
    // lane i slots 8i..8i+7 -> natural cols {base..base+3} (even slot) and
    // {base+16..base+19} (odd slot), base = 32(i>>2)+4(i&3)
    const int base = 32 * (i >> 2) + 4 * (i & 3);
    float4 wE = *(const float4*)&We2[base];
    float4 wO = *(const float4*)&We2[base + 16];
    f32x2 w01 = {wE.x, wO.x};
    f32x2 w23 = {wE.y, wO.y};
    f32x2 w45 = {wE.z, wO.z};
    f32x2 w67 = {wE.w, wO.w};
    const float B2SC = be2[0] * SC;
    const f32x2 zero2 = {0.f, 0.f};

    const int beg = offs[node], end = offs[node + 1];
    float a0 = 0.f, a1 = 0.f, a2 = 0.f, a3 = 0.f;
    float a4 = 0.f, a5 = 0.f, a6 = 0.f, a7 = 0.f;
    float zacc = 0.f, zs = 0.f;

    int s = ssrc[beg + g];  // ssrc padded: any over-read yields a valid index
    for (int e0 = beg; e0 < end; e0 += 4) {
        const bool act = (e0 + g) < end;
        const unsigned char* row = &KV[(size_t)s * KVS];
        uint2 kk = *(const uint2*)&row[8 * i];
        uint2 vv = *(const uint2*)&row[128 + 8 * i];
        float scl = Sb[s];
        s = ssrc[e0 + 4 + g];  // unguarded prefetch (pad keeps it valid)

        f32x2 d, p2;
        d = __builtin_amdgcn_cvt_pk_f32_fp8(kk.x, false) - q01;
        d = __builtin_elementwise_max(d, zero2);
        p2 = d * w01;
        d = __builtin_amdgcn_cvt_pk_f32_fp8(kk.x, true) - q23;
        d = __builtin_elementwise_max(d, zero2);
        p2 += d * w23;
        d = __builtin_amdgcn_cvt_pk_f32_fp8(kk.y, false) - q45;
        d = __builtin_elementwise_max(d, zero2);
        p2 += d * w45;
        d = __builtin_amdgcn_cvt_pk_f32_fp8(kk.y, true) - q67;
        d = __builtin_elementwise_max(d, zero2);
        p2 += d * w67;
        float p = p2[0] + p2[1];
#pragma unroll
        for (int off = 1; off <= 8; off <<= 1) p += __shfl_xor(p, off);

        float targ = fmaf(p, SC, B2SC);
        targ = fminf(fmaxf(targ, -CL), CL);
        float sc = act ? exp2f(targ) : 0.f;
        float scsc = sc * scl;
        zacc += sc;
        zs += scsc;

        a0 = fmaf(ub0(vv.x), scsc, a0);
        a1 = fmaf(ub1(vv.x), scsc, a1);
        a2 = fmaf(ub2(vv.x), scsc, a2);
        a3 = fmaf(ub3(vv.x), scsc, a3);
        a4 = fmaf(ub0(vv.y), scsc, a4);
        a5 = fmaf(ub1(vv.y), scsc, a5);
        a6 = fmaf(ub2(vv.y), scsc, a6);
        a7 = fmaf(ub3(vv.y), scsc, a7);
    }

    // cross-group combine (per-lane slots: same i across groups)
    a0 += __shfl_xor(a0, 16); a0 += __shfl_xor(a0, 32);
    a1 += __shfl_xor(a1, 16); a1 += __shfl_xor(a1, 32);
    a2 += __shfl_xor(a2, 16); a2 += __shfl_xor(a2, 32);
    a3 += __shfl_xor(a3, 16); a3 += __shfl_xor(a3, 32);
    a4 += __shfl_xor(a4, 16); a4 += __shfl_xor(a4, 32);
    a5 += __shfl_xor(a5, 16); a5 += __shfl_xor(a5, 32);
    a6 += __shfl_xor(a6, 16); a6 += __shfl_xor(a6, 32);
    a7 += __shfl_xor(a7, 16); a7 += __shfl_xor(a7, 32);
    zacc += __shfl_xor(zacc, 16); zacc += __shfl_xor(zacc, 32);
    zs += __shfl_xor(zs, 16); zs += __shfl_xor(zs, 32);

    if (g == 0) {
        float corr = 128.0f * zs;  // debias: true = acc - 128*zs
        float rz = 1.0f / zacc;
        float4 bA = *(const float4*)&bo[base];
        float4 bB = *(const float4*)&bo[base + 16];
        // slots 8i+r: r even -> cols base+(r>>1); r odd -> cols base+16+(r>>1)
        float4 oA = make_float4(fmaf(a0 - corr, rz, bA.x), fmaf(a2 - corr, rz, bA.y),
                                fmaf(a4 - corr, rz, bA.z), fmaf(a6 - corr, rz, bA.w));
        float4 oB = make_float4(fmaf(a1 - corr, rz, bB.x), fmaf(a3 - corr, rz, bB.y),
                                fmaf(a5 - corr, rz, bB.z), fmaf(a7 - corr, rz, bB.w));
        float* orow = &out[(size_t)node * DD];
        *(float4*)&orow[base] = oA;
        *(float4*)&orow[base + 16] = oB;
    }
}

// ---------------------------------------------------------------------------
extern "C" void kernel_launch(void* const* d_in, const int* in_sizes, int n_in,
                              void* d_out, int out_size, void* d_ws, size_t ws_size,
                              hipStream_t stream) {
    const float* h   = (const float*)d_in[0];
    const float* c   = (const float*)d_in[1];
    const int*   src = (const int*)d_in[2];
    const int*   dst = (const int*)d_in[3];
    const float* Wq  = (const float*)d_in[4];
    const float* Wk  = (const float*)d_in[5];
    const float* Wv  = (const float*)d_in[6];
    const float* Wp1 = (const float*)d_in[7];
    const float* bp1 = (const float*)d_in[8];
    const float* Wp2 = (const float*)d_in[9];
    const float* bp2 = (const float*)d_in[10];
    const float* We1 = (const float*)d_in[11];
    const float* be1 = (const float*)d_in[12];
    const float* We2 = (const float*)d_in[13];
    const float* be2 = (const float*)d_in[14];
    const float* Wo  = (const float*)d_in[15];
    const float* bo  = (const float*)d_in[16];

    const int N = in_sizes[0] / DD;
    const int E = in_sizes[2];
    const int NR = (N + 511) >> 9;        // 512-node buckets
    const int NB1 = (E + 4095) / 4096;    // p1 blocks
    const int NG = (N + 63) / 64;         // GEMM blocks

    u32* BF    = (u32*)d_ws;                       // 120*256 u32 (122880 B, 256-mult)
    u32* QWb   = BF + 120 * 256;                   // N*64 u32 (256B/node)
    unsigned char* KV = (unsigned char*)(QWb + (size_t)N * 64);  // N*256 B, 256-aligned
    float* Sb  = (float*)(KV + (size_t)N * KVS);   // N f32 (per-node scale)
    int* offs  = (int*)(Sb + (size_t)N);           // NR*512+1
    int* gcount = offs + ((size_t)NR * 512 + 1);   // 256
    int* ssrc   = gcount + 256;                    // E + 8 (padded)
    u32* ebuf   = (u32*)(ssrc + (E + 8));          // 256*CAP

    hipMemsetAsync(gcount, 0, 256 * sizeof(int), stream);

    fused_pre<<<30 + NB1, 256, 0, stream>>>(Wq, Wk, Wv, We1, be1, Wp2, bp2, Wo,
                                            BF, src, dst, gcount, ebuf, E);

    fused_mid<<<NR + NG, 256, 0, stream>>>(
        h, c, Wp1, bp1, BF, QWb, KV, Sb, N,
        gcount, ebuf, ssrc, offs, E, NR);

    aggregate<<<(N * 64 + 255) / 256, 256, 0, stream>>>(
        offs, ssrc, KV, Sb, QWb, We2, be2, bo, (float*)d_out, N);
}

// Round 18
// 191.817 us; speedup vs baseline: 1.0560x; 1.0560x over previous
//
#include <hip/hip_runtime.h>
#include <math.h>

#define DD 128
#define CAP 10240
#define KVS 256  // KV row: 128 K-fp8 + 128 V-u8, 256B-aligned (exactly 4 lines)
typedef unsigned int u32;
typedef unsigned short u16;
typedef __attribute__((ext_vector_type(8))) short bf16x8;
typedef __attribute__((ext_vector_type(4))) float f32x4;
typedef __attribute__((ext_vector_type(2))) float f32x2;

__device__ __forceinline__ float4 f4zero() { return make_float4(0.f, 0.f, 0.f, 0.f); }
// round-to-nearest-even f32 -> bf16 (low 16 bits)
__device__ __forceinline__ u32 bf16rne(float f) {
    u32 u = __float_as_uint(f);
    u += 0x7FFFu + ((u >> 16) & 1u);
    return u >> 16;
}
__device__ __forceinline__ u32 pack2(float lo, float hi) {
    return bf16rne(lo) | (bf16rne(hi) << 16);
}
__device__ __forceinline__ float unlo(u32 u) { return __uint_as_float(u << 16); }
__device__ __forceinline__ float unhi(u32 u) { return __uint_as_float(u & 0xFFFF0000u); }
// byte -> float; LLVM pattern-matches to v_cvt_f32_ubyte0..3
__device__ __forceinline__ float ub0(u32 v) { return (float)(v & 0xFFu); }
__device__ __forceinline__ float ub1(u32 v) { return (float)((v >> 8) & 0xFFu); }
__device__ __forceinline__ float ub2(u32 v) { return (float)((v >> 16) & 0xFFu); }
__device__ __forceinline__ float ub3(u32 v) { return (float)(v >> 24); }

// ---------------------------------------------------------------------------
// Fused pre: compose_frags (blocks 0..29, 4 sub-bids each = 120) || p1_bucket.
// B' sections: Q = Wq@We1 ; K = Wk@We1 / Wp2@We1 / bp2@We1+be1 ;
//              V = Wv@Wo / Wp2@Wo / bp2@Wo   (VPo folding)
// ---------------------------------------------------------------------------
__global__ __launch_bounds__(256) void fused_pre(
    const float* __restrict__ Wq, const float* __restrict__ Wk,
    const float* __restrict__ Wv, const float* __restrict__ We1,
    const float* __restrict__ be1, const float* __restrict__ Wp2,
    const float* __restrict__ bp2, const float* __restrict__ Wo,
    u32* __restrict__ BF,
    const int* __restrict__ src, const int* __restrict__ dst,
    int* __restrict__ gcount, u32* __restrict__ ebuf, int E) {
    const int t = threadIdx.x;
    if (blockIdx.x < 30) {
        const int bid = blockIdx.x * 4 + (t >> 6);  // 0..119
        const int l = t & 63;
        const int c = l & 15;
        const int kg = l >> 4;
        float val[8];

        const int ct = bid / 5, ks = bid - ct * 5;
        const int u = ct / 6, r = ct - u * 6;
        const int n = 32 * u + 16 * (r < 2 ? r : (r & 1)) + c;
#pragma unroll
        for (int j = 0; j < 8; ++j) {
            const int k = ks * 32 + kg * 8 + j;
            float v = 0.f;
            if (r < 2) {  // Q section
                if (k < 128) {
                    float a = 0.f;
                    for (int q = 0; q < 128; ++q)
                        a = fmaf(Wq[k * 128 + q], We1[q * 128 + n], a);
                    v = a;
                }
            } else if (r < 4) {  // K section
                if (k < 128) {
                    float a = 0.f;
                    for (int q = 0; q < 128; ++q)
                        a = fmaf(Wk[k * 128 + q], We1[q * 128 + n], a);
                    v = a;
                } else if (k < 131) {
                    float a = 0.f;
                    for (int q = 0; q < 128; ++q)
                        a = fmaf(Wp2[(k - 128) * 128 + q], We1[q * 128 + n], a);
                    v = a;
                } else if (k == 131) {
                    float a = be1[n];
                    for (int q = 0; q < 128; ++q)
                        a = fmaf(bp2[q], We1[q * 128 + n], a);
                    v = a;
                }
            } else {  // V section -> VPo rows (folded with Wo)
                if (k < 128) {
                    float a = 0.f;
                    for (int q = 0; q < 128; ++q)
                        a = fmaf(Wv[k * 128 + q], Wo[q * 128 + n], a);
                    v = a;
                } else if (k < 131) {
                    float a = 0.f;
                    for (int q = 0; q < 128; ++q)
                        a = fmaf(Wp2[(k - 128) * 128 + q], Wo[q * 128 + n], a);
                    v = a;
                } else if (k == 131) {
                    float a = 0.f;
                    for (int q = 0; q < 128; ++q)
                        a = fmaf(bp2[q], Wo[q * 128 + n], a);
                    v = a;
                }
            }
            val[j] = v;
        }
        u32* dp = &BF[((size_t)bid * 64 + l) * 4];
        dp[0] = pack2(val[0], val[1]);
        dp[1] = pack2(val[2], val[3]);
        dp[2] = pack2(val[4], val[5]);
        dp[3] = pack2(val[6], val[7]);
    } else {
        // ---- p1_bucket: LDS-ranked coarse bucket (dst>>9) ----
        __shared__ int hist[256];
        __shared__ int base[256];
        hist[t] = 0;
        __syncthreads();
        const int chunk = (blockIdx.x - 30) * 4096;
        int bk[16], rk[16];
        u32 pv[16];
#pragma unroll
        for (int i = 0; i < 16; ++i) {
            int idx = chunk + i * 256 + t;
            bk[i] = -1;
            if (idx < E) {
                int dd = dst[idx];
                int ss = src[idx];
                bk[i] = dd >> 9;
                pv[i] = ((u32)ss << 9) | (u32)(dd & 511);
                rk[i] = atomicAdd(&hist[bk[i]], 1);
            }
        }
        __syncthreads();
        if (hist[t]) base[t] = t * CAP + atomicAdd(&gcount[t], hist[t]);
        __syncthreads();
#pragma unroll
        for (int i = 0; i < 16; ++i) {
            if (bk[i] >= 0) ebuf[base[bk[i]] + rk[i]] = pv[i];
        }
    }
}

// ---------------------------------------------------------------------------
// scanB + We2 reorder into slot order.
// ---------------------------------------------------------------------------
__global__ __launch_bounds__(256) void scanB_we2r(
    const int* __restrict__ gcount, int* __restrict__ bucket_base,
    const float* __restrict__ We2, float* __restrict__ We2r) {
    __shared__ int s[256];
    int t = threadIdx.x;
    int orig = gcount[t];
    s[t] = orig;
    __syncthreads();
    for (int off = 1; off < 256; off <<= 1) {
        int x = (t >= off) ? s[t - off] : 0;
        __syncthreads();
        s[t] += x;
        __syncthreads();
    }
    bucket_base[t] = s[t] - orig;
    if (t < 128) {
        int col = 32 * (t >> 5) + 16 * (t & 1) + ((t & 31) >> 1);
        We2r[t] = We2[col];
    }
}

// ---------------------------------------------------------------------------
// Fused mid: p2_local (blocks 0..NR-1) || node_mfma (rest).
// GEMM epilogue: QWb bf16-pair; KV row (256 B): [0,128) K fp8 slot-ordered,
// [128,256) VPo int8 (biased u8). PER-NODE scale -> Sb[N] (400 KB, L2-resident
// in aggregate). Scale via wave shfl-reduce + non-atomic LDS cross-wave max.
// ---------------------------------------------------------------------------
__global__ __launch_bounds__(256) void fused_mid(
    const float* __restrict__ h, const float* __restrict__ c,
    const float* __restrict__ Wp1, const float* __restrict__ bp1,
    const u32* __restrict__ BF,
    u32* __restrict__ QWb, unsigned char* __restrict__ KV,
    float* __restrict__ Sb, int N,
    const int* __restrict__ gcount, const int* __restrict__ bucket_base,
    const u32* __restrict__ ebuf, int* __restrict__ ssrc,
    int* __restrict__ offs, int E, int NR) {
    __shared__ u32 lds[64 * 96];  // 24 KB, aliased by both paths
    const int t = threadIdx.x;

    if ((int)blockIdx.x < NR) {
        // ---- p2_local: per-bucket CSR finalize ----
        int* cnt = (int*)lds;        // 512
        int* cur = cnt + 512;        // 512
        int* ts = cur + 512;         // 256
        const int r = blockIdx.x;
        const int cnt_r = gcount[r];
        const int base_r = bucket_base[r];
        cnt[t] = 0;
        cnt[t + 256] = 0;
        __syncthreads();
        const u32* eb = &ebuf[(size_t)r * CAP];
        for (int i = t; i < cnt_r; i += 256) atomicAdd(&cnt[eb[i] & 511], 1);
        __syncthreads();
        int v0 = cnt[2 * t], v1 = cnt[2 * t + 1];
        int pair = v0 + v1;
        ts[t] = pair;
        __syncthreads();
        for (int off = 1; off < 256; off <<= 1) {
            int x = (t >= off) ? ts[t - off] : 0;
            __syncthreads();
            ts[t] += x;
            __syncthreads();
        }
        int ex = ts[t] - pair;
        cur[2 * t] = ex;
        cur[2 * t + 1] = ex + v0;
        offs[r * 512 + 2 * t] = base_r + ex;
        offs[r * 512 + 2 * t + 1] = base_r + ex + v0;
        if (r == NR - 1 && t == 255) offs[NR * 512] = E;
        __syncthreads();
        for (int i = t; i < cnt_r; i += 256) {
            u32 e = eb[i];
            int p = atomicAdd(&cur[e & 511], 1);
            ssrc[base_r + p] = (int)(e >> 9);
        }
    } else {
        // ---- node_mfma: [N x 160] @ [160 x 384] bf16 MFMA GEMM ----
        u32* hs = lds;
        const int row0 = ((int)blockIdx.x - NR) * 64;

#pragma unroll
        for (int i = 0; i < 8; ++i) {
            int f = t + i * 256;
            int row = f >> 5;
            int cq = f & 31;
            float4 v = f4zero();
            if (row0 + row < N) v = *(const float4*)&h[(size_t)(row0 + row) * DD + cq * 4];
            int idx = row * 96 + ((cq * 2) ^ ((row & 7) << 2));
            uint2 p;
            p.x = pack2(v.x, v.y);
            p.y = pack2(v.z, v.w);
            *(uint2*)&hs[idx] = p;
        }
        if (t < 64) {
            int row = t;
            float u0 = 0.f, u1 = 0.f, u2 = 0.f;
            if (row0 + row < N) {
                const float* cr = &c[(size_t)(row0 + row) * 3];
                float c0 = cr[0], c1 = cr[1], c2 = cr[2];
                u0 = fmaxf(bp1[0] + c0 * Wp1[0] + c1 * Wp1[3] + c2 * Wp1[6], 0.f);
                u1 = fmaxf(bp1[1] + c0 * Wp1[1] + c1 * Wp1[4] + c2 * Wp1[7], 0.f);
                u2 = fmaxf(bp1[2] + c0 * Wp1[2] + c1 * Wp1[5] + c2 * Wp1[8], 0.f);
            }
            int swz = (row & 7) << 2;
            uint4 z0 = make_uint4(pack2(u0, u1), pack2(u2, 1.0f), 0u, 0u);
            uint4 zz = make_uint4(0u, 0u, 0u, 0u);
#pragma unroll
            for (int q = 0; q < 4; ++q) {
                int idx = row * 96 + 64 + ((q * 4) ^ swz);
                *(uint4*)&hs[idx] = (q == 0) ? z0 : zz;
            }
        }
        __syncthreads();

        const int w = t >> 6, l = t & 63;
        const int cc = l & 15, kg = l >> 4;

        f32x4 acc[4][6];
#pragma unroll
        for (int rt = 0; rt < 4; ++rt)
#pragma unroll
            for (int r = 0; r < 6; ++r) acc[rt][r] = (f32x4){0.f, 0.f, 0.f, 0.f};

#pragma unroll
        for (int ks = 0; ks < 5; ++ks) {
            bf16x8 a[4];
#pragma unroll
            for (int rt = 0; rt < 4; ++rt) {
                int row = rt * 16 + cc;
                int idx = row * 96 + ((ks * 16 + kg * 4) ^ ((row & 7) << 2));
                a[rt] = *(const bf16x8*)&hs[idx];
            }
#pragma unroll
            for (int r = 0; r < 6; ++r) {
                const bf16x8 b = *(const bf16x8*)&BF[(((size_t)(w * 6 + r) * 5 + ks) * 64 + l) * 4];
#pragma unroll
                for (int rt = 0; rt < 4; ++rt)
                    acc[rt][r] = __builtin_amdgcn_mfma_f32_16x16x32_bf16(a[rt], b, acc[rt][r], 0, 0, 0);
            }
        }

        // ---- per-row |V|max: shfl-reduce over 16 cc-lanes, then non-atomic
        //      cross-wave max via LDS (distinct slots, no contention) ----
        __syncthreads();  // all waves done reading hs
        float* ldsM = (float*)lds;  // [64 rows][4 waves]
#pragma unroll
        for (int rt = 0; rt < 4; ++rt) {
#pragma unroll
            for (int j = 0; j < 4; ++j) {
                float m = fmaxf(fabsf(acc[rt][4][j]), fabsf(acc[rt][5][j]));
                m = fmaxf(m, __shfl_xor(m, 1));
                m = fmaxf(m, __shfl_xor(m, 2));
                m = fmaxf(m, __shfl_xor(m, 4));
                m = fmaxf(m, __shfl_xor(m, 8));
                if (cc == 0) ldsM[(rt * 16 + kg * 4 + j) * 4 + w] = m;
            }
        }
        __syncthreads();

#pragma unroll
        for (int rt = 0; rt < 4; ++rt) {
#pragma unroll
            for (int j = 0; j < 4; ++j) {
                int rl = rt * 16 + kg * 4 + j;
                int row = row0 + rl;
                if (row >= N) continue;
                float smax = fmaxf(fmaxf(ldsM[rl * 4 + 0], ldsM[rl * 4 + 1]),
                                   fmaxf(ldsM[rl * 4 + 2], ldsM[rl * 4 + 3]));
                float scale = (smax > 0.f) ? smax * (1.0f / 127.0f) : 1.0f;
                float rsc = 1.0f / scale;
                QWb[(size_t)row * 64 + w * 16 + cc] = pack2(acc[rt][0][j], acc[rt][1][j]);
                unsigned char* kvrow = &KV[(size_t)row * KVS];
                u32 kp = __builtin_amdgcn_cvt_pk_fp8_f32(acc[rt][2][j], acc[rt][3][j], 0u, false);
                *(u16*)&kvrow[w * 32 + cc * 2] = (u16)kp;
                int q0 = (int)rintf(acc[rt][4][j] * rsc) + 128;
                int q1 = (int)rintf(acc[rt][5][j] * rsc) + 128;
                *(u16*)&kvrow[128 + 2 * (w * 16 + cc)] = (u16)((q0 & 0xFF) | ((q1 & 0xFF) << 8));
                if (w == 0 && cc == 0) Sb[row] = scale;
            }
        }
    }
}

// ---------------------------------------------------------------------------
// Aggregate: quarter-wave (16-lane) groups, 4 edges in flight/wave.
// Gathers 256B-aligned KV row (fp8 K 8B + u8 V 8B per lane) + per-NODE scale
// from Sb[N] (400 KB -> L2 hit). Debias with 128*zs. Writes fp32 out directly.
// ---------------------------------------------------------------------------
__global__ __launch_bounds__(256) void aggregate(
    const int* __restrict__ offs, const int* __restrict__ ssrc,
    const unsigned char* __restrict__ KV, const float* __restrict__ Sb,
    const u32* __restrict__ QWb, const float* __restrict__ We2r,
    const float* __restrict__ be2, const float* __restrict__ bo,
    float* __restrict__ out, int N) {
    const int node = (blockIdx.x * 256 + threadIdx.x) >> 6;
    const int lane = threadIdx.x & 63;
    if (node >= N) return;
    const int g = lane >> 4, i = lane & 15;

    const float SC = 0.08838834764831845f * 1.4426950408889634f;  // (1/sqrt128)*log2e
    const float CL = 5.0f * 1.4426950408889634f;

    uint4 Qu = *(const uint4*)&QWb[(size_t)node * 64 + 4 * i];
    f32x2 q01 = {unlo(Qu.x), unhi(Qu.x)};
    f32x2 q23 = {unlo(Qu.y), unhi(Qu.y)};
    f32x2 q45 = {unlo(Qu.z), unhi(Qu.z)};
    f32x2 q67 = {unlo(Qu.w), unhi(Qu.w)};
    f32x2 w01 = *(const f32x2*)&We2r[8 * i];
    f32x2 w23 = *(const f32x2*)&We2r[8 * i + 2];
    f32x2 w45 = *(const f32x2*)&We2r[8 * i + 4];
    f32x2 w67 = *(const f32x2*)&We2r[8 * i + 6];
    const float B2SC = be2[0] * SC;
    const f32x2 zero2 = {0.f, 0.f};

    const int beg = offs[node], end = offs[node + 1];
    float a0 = 0.f, a1 = 0.f, a2 = 0.f, a3 = 0.f;
    float a4 = 0.f, a5 = 0.f, a6 = 0.f, a7 = 0.f;
    float zacc = 0.f, zs = 0.f;

    int e = beg + g;
    int s = (e < end) ? ssrc[e] : 0;
    for (int e0 = beg; e0 < end; e0 += 4) {
        const bool act = (e0 + g) < end;
        const unsigned char* row = &KV[(size_t)s * KVS];
        uint2 kk = *(const uint2*)&row[8 * i];
        uint2 vv = *(const uint2*)&row[128 + 8 * i];
        float scl = Sb[s];
        int en = e0 + 4 + g;
        s = (en < end) ? ssrc[en] : 0;  // prefetch next group edge index

        f32x2 d, p2;
        d = __builtin_amdgcn_cvt_pk_f32_fp8(kk.x, false) - q01;
        d = __builtin_elementwise_max(d, zero2);
        p2 = d * w01;
        d = __builtin_amdgcn_cvt_pk_f32_fp8(kk.x, true) - q23;
        d = __builtin_elementwise_max(d, zero2);
        p2 += d * w23;
        d = __builtin_amdgcn_cvt_pk_f32_fp8(kk.y, false) - q45;
        d = __builtin_elementwise_max(d, zero2);
        p2 += d * w45;
        d = __builtin_amdgcn_cvt_pk_f32_fp8(kk.y, true) - q67;
        d = __builtin_elementwise_max(d, zero2);
        p2 += d * w67;
        float p = p2[0] + p2[1];
#pragma unroll
        for (int off = 1; off <= 8; off <<= 1) p += __shfl_xor(p, off);

        float targ = fmaf(p, SC, B2SC);
        targ = fminf(fmaxf(targ, -CL), CL);
        float sc = act ? exp2f(targ) : 0.f;
        float scsc = sc * scl;
        zacc += sc;
        zs += scsc;

        a0 = fmaf(ub0(vv.x), scsc, a0);
        a1 = fmaf(ub1(vv.x), scsc, a1);
        a2 = fmaf(ub2(vv.x), scsc, a2);
        a3 = fmaf(ub3(vv.x), scsc, a3);
        a4 = fmaf(ub0(vv.y), scsc, a4);
        a5 = fmaf(ub1(vv.y), scsc, a5);
        a6 = fmaf(ub2(vv.y), scsc, a6);
        a7 = fmaf(ub3(vv.y), scsc, a7);
    }

    // cross-group combine (per-lane slots: same i across groups)
    a0 += __shfl_xor(a0, 16); a0 += __shfl_xor(a0, 32);
    a1 += __shfl_xor(a1, 16); a1 += __shfl_xor(a1, 32);
    a2 += __shfl_xor(a2, 16); a2 += __shfl_xor(a2, 32);
    a3 += __shfl_xor(a3, 16); a3 += __shfl_xor(a3, 32);
    a4 += __shfl_xor(a4, 16); a4 += __shfl_xor(a4, 32);
    a5 += __shfl_xor(a5, 16); a5 += __shfl_xor(a5, 32);
    a6 += __shfl_xor(a6, 16); a6 += __shfl_xor(a6, 32);
    a7 += __shfl_xor(a7, 16); a7 += __shfl_xor(a7, 32);
    zacc += __shfl_xor(zacc, 16); zacc += __shfl_xor(zacc, 32);
    zs += __shfl_xor(zs, 16); zs += __shfl_xor(zs, 32);

    if (g == 0) {
        float corr = 128.0f * zs;  // debias: true = acc - 128*zs
        float rz = 1.0f / zacc;
        const int base = 32 * (i >> 2) + 4 * (i & 3);
        float4 bA = *(const float4*)&bo[base];
        float4 bB = *(const float4*)&bo[base + 16];
        // slots 8i+r: r even -> cols base+(r>>1); r odd -> cols base+16+(r>>1)
        float4 oA = make_float4(fmaf(a0 - corr, rz, bA.x), fmaf(a2 - corr, rz, bA.y),
                                fmaf(a4 - corr, rz, bA.z), fmaf(a6 - corr, rz, bA.w));
        float4 oB = make_float4(fmaf(a1 - corr, rz, bB.x), fmaf(a3 - corr, rz, bB.y),
                                fmaf(a5 - corr, rz, bB.z), fmaf(a7 - corr, rz, bB.w));
        float* orow = &out[(size_t)node * DD];
        *(float4*)&orow[base] = oA;
        *(float4*)&orow[base + 16] = oB;
    }
}

// ---------------------------------------------------------------------------
extern "C" void kernel_launch(void* const* d_in, const int* in_sizes, int n_in,
                              void* d_out, int out_size, void* d_ws, size_t ws_size,
                              hipStream_t stream) {
    const float* h   = (const float*)d_in[0];
    const float* c   = (const float*)d_in[1];
    const int*   src = (const int*)d_in[2];
    const int*   dst = (const int*)d_in[3];
    const float* Wq  = (const float*)d_in[4];
    const float* Wk  = (const float*)d_in[5];
    const float* Wv  = (const float*)d_in[6];
    const float* Wp1 = (const float*)d_in[7];
    const float* bp1 = (const float*)d_in[8];
    const float* Wp2 = (const float*)d_in[9];
    const float* bp2 = (const float*)d_in[10];
    const float* We1 = (const float*)d_in[11];
    const float* be1 = (const float*)d_in[12];
    const float* We2 = (const float*)d_in[13];
    const float* be2 = (const float*)d_in[14];
    const float* Wo  = (const float*)d_in[15];
    const float* bo  = (const float*)d_in[16];

    const int N = in_sizes[0] / DD;
    const int E = in_sizes[2];
    const int NR = (N + 511) >> 9;        // 512-node buckets
    const int NB1 = (E + 4095) / 4096;    // p1 blocks
    const int NG = (N + 63) / 64;         // GEMM blocks

    u32* BF    = (u32*)d_ws;                       // 120*256 u32 (122880 B, 256-mult)
    u32* QWb   = BF + 120 * 256;                   // N*64 u32 (256B/node)
    unsigned char* KV = (unsigned char*)(QWb + (size_t)N * 64);  // N*256 B, 256-aligned
    float* Sb  = (float*)(KV + (size_t)N * KVS);   // N f32 (per-node scale)
    int* offs  = (int*)(Sb + (size_t)N);           // NR*512+1
    int* gcount = offs + ((size_t)NR * 512 + 1);   // 256
    int* bbase  = gcount + 256;                    // 256
    float* We2r = (float*)(bbase + 256);           // 128
    int* ssrc   = (int*)(We2r + 128);              // E
    u32* ebuf   = (u32*)(ssrc + E);                // 256*CAP

    hipMemsetAsync(gcount, 0, 256 * sizeof(int), stream);

    fused_pre<<<30 + NB1, 256, 0, stream>>>(Wq, Wk, Wv, We1, be1, Wp2, bp2, Wo,
                                            BF, src, dst, gcount, ebuf, E);

    scanB_we2r<<<1, 256, 0, stream>>>(gcount, bbase, We2, We2r);

    fused_mid<<<NR + NG, 256, 0, stream>>>(
        h, c, Wp1, bp1, BF, QWb, KV, Sb, N,
        gcount, bbase, ebuf, ssrc, offs, E, NR);

    aggregate<<<(N * 64 + 255) / 256, 256, 0, stream>>>(
        offs, ssrc, KV, Sb, QWb, We2r, be2, bo, (float*)d_out, N);
}